// Round 2
// baseline (674.137 us; speedup 1.0000x reference)
//
#include <hip/hip_runtime.h>
#include <hip/hip_cooperative_groups.h>

namespace cg = cooperative_groups;

#define NBATCH 16
#define NCH 64
#define NGRP 16
#define CPGV 4
#define EPSV 1e-5f
#define GRID_BLKS 1024   // 4 blocks/CU x 256 CUs -> co-resident with __launch_bounds__(256,4)

// ws layout (bytes):
//   0    : S1  [16][64] float (4096)
//   4096 : S2  [16][64] float (4096)
//   8192 : cnt [16] int       (64)

__global__ void __launch_bounds__(256, 4)
ogn_fused(const float* __restrict__ data,
          const int* __restrict__ bidp,
          const float* __restrict__ w,
          const float* __restrict__ bias,
          float* __restrict__ out,
          float* __restrict__ S1,
          float* __restrict__ S2,
          int* __restrict__ cnt,
          int N, int rows_per_block) {
    cg::grid_group grid = cg::this_grid();

    __shared__ __align__(16) float ls1[NBATCH * NCH];  // phase1: S1 accum; phase3: A table
    __shared__ __align__(16) float ls2[NBATCH * NCH];  // phase1: S2 accum; phase3: B table
    __shared__ int lcnt[NBATCH];

    const int t = threadIdx.x;

    // ---- phase 0: zero global accumulators (poisoned 0xAA by harness) ----
    long long gtid = (long long)blockIdx.x * blockDim.x + t;
    if (gtid < NBATCH * NCH) { S1[gtid] = 0.f; S2[gtid] = 0.f; }
    if (gtid < NBATCH) cnt[gtid] = 0;

    for (int i = t; i < NBATCH * NCH; i += 256) { ls1[i] = 0.f; ls2[i] = 0.f; }
    if (t < NBATCH) lcnt[t] = 0;

    grid.sync();  // global zeros visible; also block barrier for LDS zeros

    // ---- phase 1: per-block stats over this block's contiguous row chunk ----
    const int c4    = t & 15;   // which float4 of the 64-ch row
    const int rlane = t >> 4;   // row within a 16-row sweep

    long long row_begin = (long long)blockIdx.x * rows_per_block;
    long long row_end   = row_begin + rows_per_block;
    if (row_end > N) row_end = N;

    const float4* data4 = (const float4*)data;

    float4 s1 = make_float4(0.f, 0.f, 0.f, 0.f);
    float4 s2 = make_float4(0.f, 0.f, 0.f, 0.f);
    int cur = -1;
    int c   = 0;

    for (long long r = row_begin + rlane; r < row_end; r += 16) {
        int b = bidp[r];
        if (b != cur) {
            if (cur >= 0) {
                int base = cur * NCH + c4 * 4;
                atomicAdd(&ls1[base + 0], s1.x);
                atomicAdd(&ls1[base + 1], s1.y);
                atomicAdd(&ls1[base + 2], s1.z);
                atomicAdd(&ls1[base + 3], s1.w);
                atomicAdd(&ls2[base + 0], s2.x);
                atomicAdd(&ls2[base + 1], s2.y);
                atomicAdd(&ls2[base + 2], s2.z);
                atomicAdd(&ls2[base + 3], s2.w);
                if (c4 == 0) atomicAdd(&lcnt[cur], c);
            }
            s1 = make_float4(0.f, 0.f, 0.f, 0.f);
            s2 = make_float4(0.f, 0.f, 0.f, 0.f);
            c = 0;
            cur = b;
        }
        float4 v = data4[r * 16 + c4];
        s1.x += v.x; s1.y += v.y; s1.z += v.z; s1.w += v.w;
        s2.x += v.x * v.x; s2.y += v.y * v.y; s2.z += v.z * v.z; s2.w += v.w * v.w;
        c++;
    }
    if (cur >= 0) {
        int base = cur * NCH + c4 * 4;
        atomicAdd(&ls1[base + 0], s1.x);
        atomicAdd(&ls1[base + 1], s1.y);
        atomicAdd(&ls1[base + 2], s1.z);
        atomicAdd(&ls1[base + 3], s1.w);
        atomicAdd(&ls2[base + 0], s2.x);
        atomicAdd(&ls2[base + 1], s2.y);
        atomicAdd(&ls2[base + 2], s2.z);
        atomicAdd(&ls2[base + 3], s2.w);
        if (c4 == 0) atomicAdd(&lcnt[cur], c);
    }
    __syncthreads();

    // push block partials to global
    for (int i = t; i < NBATCH * NCH; i += 256) {
        float v1 = ls1[i];
        float v2 = ls2[i];
        if (v1 != 0.f) atomicAdd(&S1[i], v1);
        if (v2 != 0.f) atomicAdd(&S2[i], v2);
    }
    if (t < NBATCH) {
        int v = lcnt[t];
        if (v != 0) atomicAdd(&cnt[t], v);
    }

    grid.sync();  // all partials in S1/S2/cnt; also guards LDS reuse below

    // ---- phase 2: every block computes the A/B tables into its LDS ----
    {
        int b = t >> 4;            // 256 threads = 16 batches x 16 groups
        int g = t & 15;
        int base = b * NCH + g * CPGV;
        float s1g = 0.f, s2g = 0.f;
#pragma unroll
        for (int k = 0; k < CPGV; ++k) {
            s1g += S1[base + k];
            s2g += S2[base + k];
        }
        float countf    = (float)cnt[b] * (float)CPGV;
        float inv_count = 1.f / (countf + EPSV);
        float mean      = s1g * inv_count;
        float var       = inv_count * (s2g - 2.f * mean * s1g + countf * mean * mean);
        float inv_std   = rsqrtf(var + EPSV);
#pragma unroll
        for (int k = 0; k < CPGV; ++k) {
            int ch = g * CPGV + k;
            float a = inv_std * w[ch];
            ls1[b * NCH + ch] = a;                      // A
            ls2[b * NCH + ch] = bias[ch] - mean * a;    // B
        }
    }
    __syncthreads();

    // ---- phase 3: apply over the SAME rows this block just read (L3-hot) ----
    float4* out4 = (float4*)out;
    cur = -1;
    float4 av = make_float4(0.f, 0.f, 0.f, 0.f);
    float4 bv = make_float4(0.f, 0.f, 0.f, 0.f);

    for (long long r = row_begin + rlane; r < row_end; r += 16) {
        int b = bidp[r];
        if (b != cur) {
            cur = b;
            int base = b * NCH + c4 * 4;
            av = *(const float4*)&ls1[base];
            bv = *(const float4*)&ls2[base];
        }
        float4 v = data4[r * 16 + c4];
        float4 o;
        o.x = fmaf(v.x, av.x, bv.x);
        o.y = fmaf(v.y, av.y, bv.y);
        o.z = fmaf(v.z, av.z, bv.z);
        o.w = fmaf(v.w, av.w, bv.w);
        out4[r * 16 + c4] = o;
    }
}

extern "C" void kernel_launch(void* const* d_in, const int* in_sizes, int n_in,
                              void* d_out, int out_size, void* d_ws, size_t ws_size,
                              hipStream_t stream) {
    const float* data = (const float*)d_in[0];
    const int*   bid  = (const int*)d_in[1];
    const float* w    = (const float*)d_in[2];
    const float* bias = (const float*)d_in[3];
    float* out = (float*)d_out;

    int N = in_sizes[1];  // batch_id element count

    char* ws = (char*)d_ws;
    float* S1  = (float*)(ws + 0);
    float* S2  = (float*)(ws + 4096);
    int*   cnt = (int*)  (ws + 8192);

    int rows_per_block = (N + GRID_BLKS - 1) / GRID_BLKS;

    void* args[] = { (void*)&data, (void*)&bid, (void*)&w, (void*)&bias,
                     (void*)&out, (void*)&S1, (void*)&S2, (void*)&cnt,
                     (void*)&N, (void*)&rows_per_block };
    hipLaunchCooperativeKernel((void*)ogn_fused, dim3(GRID_BLKS), dim3(256),
                               args, 0, stream);
}